// Round 9
// baseline (36.458 us; speedup 1.0000x reference)
//
#include <hip/hip_runtime.h>

// Problem: B=4096, N=16, E=512. Outputs: aggregated (B,E) then weights (B,N), f32.
//
// task_anchor @ v_t is a per-b constant across the softmax axis -> dead input
// (softmax shift invariance). Traffic floor: 134.2 MB read + 8.9 MB write.
//
// R9 = R8 (best, 26.01 us; 64-VGPR / 8 waves-SIMD structure unchanged) +
// persistent one-cohort grid: 2048 blocks (= exactly 8 resident blocks/CU x
// 256 CU), each looping over b and b+2048. Halves launches, removes the
// mid-kernel cohort boundary and drain. lds_s double-buffered per iteration
// (no extra barrier); #pragma unroll 1 keeps one tile instance (VGPR <= 64).

#define NB 4096
#define NEXP 16
#define EDIM 512
#define NBLK 2048

typedef float f32x2 __attribute__((ext_vector_type(2)));

__global__ __launch_bounds__(256, 8) void meta_attn_kernel(
    const float* __restrict__ expert,   // [B, 16, 512]
    const float* __restrict__ v,        // [640, 1]; v_e = v[0:512]
    float* __restrict__ out_agg,        // [B, 512]
    float* __restrict__ out_w)          // [B, 16]
{
    const int wave = threadIdx.x >> 6;
    const int lane = threadIdx.x & 63;
    const int eoff = 128 * wave + 2 * lane;            // this thread's e-offset

    const f32x2 ve = *(const f32x2*)(v + eoff);        // loaded once, reused

    __shared__ float lds_s[2][NEXP][4];                // per-iteration buffer

#pragma unroll 1
    for (int it = 0; it < 2; ++it) {
        const int b = blockIdx.x + it * NBLK;
        const float* row = expert + (size_t)b * (NEXP * EDIM) + eoff;

        // Register tile: this thread's float2 of every row (32 VGPRs)
        f32x2 tile[NEXP];
#pragma unroll
        for (int n = 0; n < NEXP; ++n)
            tile[n] = __builtin_nontemporal_load((const f32x2*)(row + n * EDIM));

        // Per-lane partial dots
        float cur[NEXP];
#pragma unroll
        for (int n = 0; n < NEXP; ++n)
            cur[n] = tile[n].x * ve.x + tile[n].y * ve.y;

        // Multi-value butterfly: 16 partials over 64 lanes in 17 shuffles
        // (verified R4). Lane ends owning score rev4(lane&15).
        float t8[8];
        {
            const bool hi = (lane & 1) != 0;
#pragma unroll
            for (int j = 0; j < 8; ++j) {
                const float send = hi ? cur[j] : cur[j + 8];
                const float keep = hi ? cur[j + 8] : cur[j];
                t8[j] = keep + __shfl_xor(send, 1, 64);
            }
        }
        float t4[4];
        {
            const bool hi = (lane & 2) != 0;
#pragma unroll
            for (int j = 0; j < 4; ++j) {
                const float send = hi ? t8[j] : t8[j + 4];
                const float keep = hi ? t8[j + 4] : t8[j];
                t4[j] = keep + __shfl_xor(send, 2, 64);
            }
        }
        float t2[2];
        {
            const bool hi = (lane & 4) != 0;
#pragma unroll
            for (int j = 0; j < 2; ++j) {
                const float send = hi ? t4[j] : t4[j + 2];
                const float keep = hi ? t4[j + 2] : t4[j];
                t2[j] = keep + __shfl_xor(send, 4, 64);
            }
        }
        float t1;
        {
            const bool hi = (lane & 8) != 0;
            const float send = hi ? t2[0] : t2[1];
            const float keep = hi ? t2[1] : t2[0];
            t1 = keep + __shfl_xor(send, 8, 64);
        }
        t1 += __shfl_xor(t1, 16, 64);
        t1 += __shfl_xor(t1, 32, 64);

        // Cross-wave combine (buffer `it`: no race with prev iteration's reads)
        if (lane < 16) {
            const int idx = ((lane & 1) << 3) | ((lane & 2) << 1) |
                            ((lane & 4) >> 1) | ((lane & 8) >> 3);
            lds_s[it][idx][wave] = t1;
        }
        __syncthreads();

        float s[NEXP];
#pragma unroll
        for (int n = 0; n < NEXP; ++n)
            s[n] = (lds_s[it][n][0] + lds_s[it][n][1]) +
                   (lds_s[it][n][2] + lds_s[it][n][3]);

        // Max for numerical stability
        float mx = s[0];
#pragma unroll
        for (int n = 1; n < NEXP; ++n) mx = fmaxf(mx, s[n]);

        // Fused exp + aggregation: unnormalized accumulate, scale at end
        f32x2 acc = {0.f, 0.f};
        float sum = 0.0f;
        float myw = 0.0f;       // wave0 lane n keeps exp(s[n]-mx)
#pragma unroll
        for (int n = 0; n < NEXP; ++n) {
            const float u = __expf(s[n] - mx);
            sum += u;
            acc.x += u * tile[n].x;
            acc.y += u * tile[n].y;
            myw = (lane == n) ? u : myw;
        }
        const float inv = 1.0f / sum;
        acc.x *= inv;
        acc.y *= inv;

        __builtin_nontemporal_store(acc, (f32x2*)(out_agg + (size_t)b * EDIM + eoff));

        if (wave == 0 && lane < NEXP)
            out_w[(size_t)b * NEXP + lane] = myw * inv;
    }
}

extern "C" void kernel_launch(void* const* d_in, const int* in_sizes, int n_in,
                              void* d_out, int out_size, void* d_ws, size_t ws_size,
                              hipStream_t stream) {
    // d_in: 0=scene_repr (unused), 1=task_anchor (unused), 2=expert_reprs, 3=v
    const float* expert = (const float*)d_in[2];
    const float* v      = (const float*)d_in[3];
    float* out_agg = (float*)d_out;
    float* out_w   = (float*)d_out + (size_t)NB * EDIM;

    meta_attn_kernel<<<dim3(NBLK), dim3(256), 0, stream>>>(expert, v, out_agg, out_w);
}

// Round 10
// 26.235 us; speedup vs baseline: 1.3897x; 1.3897x over previous
//
#include <hip/hip_runtime.h>

// Problem: B=4096, N=16, E=512. Outputs: aggregated (B,E) then weights (B,N), f32.
//
// task_anchor @ v_t is a per-b constant across the softmax axis -> dead input
// (softmax shift invariance). Traffic floor: 134.2 MB read + 8.9 MB write.
//
// R10 = exact revert to R8 (best measured: 26.01 us, 5.49 TB/s):
//  - one block (4 waves) per b; wave w owns e-slice [128w,128w+128)
//  - 32-VGPR register tile; fused exp+aggregation (no persistent w[16])
//  - __launch_bounds__(256,8): VGPR <= 64 -> 8 waves/SIMD (m69 breakpoint)
//  - 17-shuffle multi-value butterfly + 256 B LDS cross-wave combine
// R9's persistent loop regressed (serialized iteration boundary); reverted.

#define NB 4096
#define NEXP 16
#define EDIM 512

typedef float f32x2 __attribute__((ext_vector_type(2)));

__global__ __launch_bounds__(256, 8) void meta_attn_kernel(
    const float* __restrict__ expert,   // [B, 16, 512]
    const float* __restrict__ v,        // [640, 1]; v_e = v[0:512]
    float* __restrict__ out_agg,        // [B, 512]
    float* __restrict__ out_w)          // [B, 16]
{
    const int wave = threadIdx.x >> 6;
    const int lane = threadIdx.x & 63;
    const int b = blockIdx.x;

    const int eoff = 128 * wave + 2 * lane;            // this thread's e-offset
    const float* row = expert + (size_t)b * (NEXP * EDIM) + eoff;

    const f32x2 ve = *(const f32x2*)(v + eoff);

    // Register tile: this thread's float2 of every row (32 VGPRs)
    f32x2 tile[NEXP];
#pragma unroll
    for (int n = 0; n < NEXP; ++n)
        tile[n] = __builtin_nontemporal_load((const f32x2*)(row + n * EDIM));

    // Per-lane partial dots
    float cur[NEXP];
#pragma unroll
    for (int n = 0; n < NEXP; ++n)
        cur[n] = tile[n].x * ve.x + tile[n].y * ve.y;

    // Multi-value butterfly: 16 partials over 64 lanes in 17 shuffles
    // (verified R4). Lane ends owning score rev4(lane&15).
    float t8[8];
    {
        const bool hi = (lane & 1) != 0;
#pragma unroll
        for (int j = 0; j < 8; ++j) {
            const float send = hi ? cur[j] : cur[j + 8];
            const float keep = hi ? cur[j + 8] : cur[j];
            t8[j] = keep + __shfl_xor(send, 1, 64);
        }
    }
    float t4[4];
    {
        const bool hi = (lane & 2) != 0;
#pragma unroll
        for (int j = 0; j < 4; ++j) {
            const float send = hi ? t8[j] : t8[j + 4];
            const float keep = hi ? t8[j + 4] : t8[j];
            t4[j] = keep + __shfl_xor(send, 2, 64);
        }
    }
    float t2[2];
    {
        const bool hi = (lane & 4) != 0;
#pragma unroll
        for (int j = 0; j < 2; ++j) {
            const float send = hi ? t4[j] : t4[j + 2];
            const float keep = hi ? t4[j + 2] : t4[j];
            t2[j] = keep + __shfl_xor(send, 4, 64);
        }
    }
    float t1;
    {
        const bool hi = (lane & 8) != 0;
        const float send = hi ? t2[0] : t2[1];
        const float keep = hi ? t2[1] : t2[0];
        t1 = keep + __shfl_xor(send, 8, 64);
    }
    t1 += __shfl_xor(t1, 16, 64);
    t1 += __shfl_xor(t1, 32, 64);

    // Cross-wave combine via 256 B LDS
    __shared__ float lds_s[NEXP][4];
    if (lane < 16) {
        const int idx = ((lane & 1) << 3) | ((lane & 2) << 1) |
                        ((lane & 4) >> 1) | ((lane & 8) >> 3);
        lds_s[idx][wave] = t1;
    }
    __syncthreads();

    float s[NEXP];
#pragma unroll
    for (int n = 0; n < NEXP; ++n)
        s[n] = (lds_s[n][0] + lds_s[n][1]) + (lds_s[n][2] + lds_s[n][3]);

    // Max for numerical stability
    float mx = s[0];
#pragma unroll
    for (int n = 1; n < NEXP; ++n) mx = fmaxf(mx, s[n]);

    // Fused exp + aggregation: unnormalized accumulate, scale at end.
    // (no persistent w[16] array -> fits the 64-VGPR occupancy breakpoint)
    f32x2 acc = {0.f, 0.f};
    float sum = 0.0f;
    float myw = 0.0f;           // wave0 lane n keeps exp(s[n]-mx)
#pragma unroll
    for (int n = 0; n < NEXP; ++n) {
        const float u = __expf(s[n] - mx);
        sum += u;
        acc.x += u * tile[n].x;
        acc.y += u * tile[n].y;
        myw = (lane == n) ? u : myw;
    }
    const float inv = 1.0f / sum;
    acc.x *= inv;
    acc.y *= inv;

    __builtin_nontemporal_store(acc, (f32x2*)(out_agg + (size_t)b * EDIM + eoff));

    if (wave == 0 && lane < NEXP)
        out_w[(size_t)b * NEXP + lane] = myw * inv;
}

extern "C" void kernel_launch(void* const* d_in, const int* in_sizes, int n_in,
                              void* d_out, int out_size, void* d_ws, size_t ws_size,
                              hipStream_t stream) {
    // d_in: 0=scene_repr (unused), 1=task_anchor (unused), 2=expert_reprs, 3=v
    const float* expert = (const float*)d_in[2];
    const float* v      = (const float*)d_in[3];
    float* out_agg = (float*)d_out;
    float* out_w   = (float*)d_out + (size_t)NB * EDIM;

    meta_attn_kernel<<<dim3(NB), dim3(256), 0, stream>>>(expert, v, out_agg, out_w);
}